// Round 15
// baseline (101.848 us; speedup 1.0000x reference)
//
#include <hip/hip_runtime.h>

#define BB 32
#define CC 768
#define SS 1024
#define LLn 77
#define DD 512
#define LP 80      // padded L for tlc rows / At rows
#define LP2 96     // padded L (K dim) for bf16 MFMA operands, mult of 32
#define WREG2 5184 // bytes per wave union: qbuf[16][136]bf16 -> qhpart[16][80]f32 -> P[16][104]bf16 -> upart[16][81]f32

#define RATIO 0.0751953125f   // 77/1024 exact in fp32

#define CVT_TXT_BLOCKS (BB * LP * DD / 4 / 256)   // 1280
#define CVT_W_BLOCKS ((CC / 32) * (DD / 32))      // 384
#define AB_BLOCKS (8 * 5 * 4 * 64 * 8 / 4 / 256)  // 80 (fragment-layout Ab, 8 K-windows)
#define TG_BLOCKS (BB * 5 * 4)                    // 640

typedef short bf16x8 __attribute__((ext_vector_type(8)));
typedef float f32x4 __attribute__((ext_vector_type(4)));
typedef float f32x2 __attribute__((ext_vector_type(2)));
typedef unsigned short u16;
typedef unsigned int u32;

#define MFMA __builtin_amdgcn_mfma_f32_16x16x32_bf16

__device__ __forceinline__ float bf2f(unsigned int h16) {
    unsigned int u = h16 << 16;
    float f; __builtin_memcpy(&f, &u, 4); return f;
}
__device__ __forceinline__ u16 f2bf(float f) {
    unsigned int u; __builtin_memcpy(&u, &f, 4);
    u += 0x7fffu + ((u >> 16) & 1u);   // RNE
    return (u16)(u >> 16);
}

// K0: converts. text -> At bf16 (padded rows); W -> Wb bf16 transposed;
//     tent-weight matrix in MFMA-fragment layout for 8 waves x 5 ntiles x 4 ksteps.
__global__ __launch_bounds__(256) void k_cvt(const float* __restrict__ text,
                                             const float* __restrict__ Wt,
                                             u16* __restrict__ At,
                                             u16* __restrict__ Wb,
                                             u16* __restrict__ Abf) {
    __shared__ float tile[32 * 33];
    const int bx = blockIdx.x;
    const int tid = threadIdx.x;
    if (bx < CVT_TXT_BLOCKS) {
        int j = bx * 256 + tid;                    // float4-granular, exact cover
        int row80 = j >> 7, col4 = (j & 127) << 2;
        int b = row80 / LP, l = row80 - b * LP;
        u16 o[4] = {0, 0, 0, 0};
        if (l < LLn) {
            float4 v = *reinterpret_cast<const float4*>(&text[((size_t)b * LLn + l) * DD + col4]);
            o[0] = f2bf(v.x); o[1] = f2bf(v.y); o[2] = f2bf(v.z); o[3] = f2bf(v.w);
        }
        *reinterpret_cast<uint2*>(&At[(size_t)row80 * DD + col4]) = *reinterpret_cast<uint2*>(o);
    } else if (bx < CVT_TXT_BLOCKS + CVT_W_BLOCKS) {
        const int bw = bx - CVT_TXT_BLOCKS;
        const int c0 = (bw % (CC / 32)) * 32, d0 = (bw / (CC / 32)) * 32;
        const int tx = tid & 31, ty = tid >> 5;    // ty 0..7
#pragma unroll
        for (int k = 0; k < 4; ++k) {
            int d = ty + k * 8;
            tile[d * 33 + tx] = Wt[(size_t)(d0 + d) * CC + c0 + tx];
        }
        __syncthreads();
#pragma unroll
        for (int k = 0; k < 4; ++k) {
            int c = ty + k * 8;
            Wb[(size_t)(c0 + c) * DD + d0 + tx] = f2bf(tile[tx * 33 + c]);
        }
    } else {
        // ---- Abf: frag f = (wv*5+nt)*4+kk, elem = f*512 + lane*8 + e ----
        int g = (bx - CVT_TXT_BLOCKS - CVT_W_BLOCKS) * 1024 + tid * 4;  // 4 e-values/thread
        int e0   = g & 7;              // 0 or 4
        int lane = (g >> 3) & 63;
        int kk   = (g >> 9) & 3;
        int wn   = g >> 11;            // wv*5 + nt
        int nt   = wn % 5;
        int wv   = wn / 5;
        int l    = nt * 16 + (lane & 15);
        int sb   = wv * 128 + kk * 32 + ((lane >> 4) << 3) + e0;
        float fl = (float)l;
        u16 o[4];
#pragma unroll
        for (int k = 0; k < 4; ++k) {
            float src = fmaf((float)(sb + k) + 0.5f, RATIO, -0.5f);
            src = fminf(fmaxf(src, 0.f), 76.f);
            o[k] = f2bf(fmaxf(0.f, 1.f - fabsf(src - fl)) * 0.03125f);
        }
        *reinterpret_cast<uint2*>(&Abf[g]) = *reinterpret_cast<uint2*>(o);
    }
}

// K1: t = text @ W, batch-aligned tiles. 640 blocks: bx -> (colgroup, b, tile).
__global__ __launch_bounds__(256) void k_tgemm(const u16* __restrict__ At,
                                               const u16* __restrict__ Wb,
                                               u16* __restrict__ tc,
                                               u16* __restrict__ tlc) {
    const int bx = blockIdx.x;
    const int tid = threadIdx.x;
    const int cg = bx / 160, mt = bx % 160;
    const int b = mt / 5, tile = mt % 5;
    const int l0 = tile * 16;
    const int w = tid >> 6, lane = tid & 63;
    const int lm = lane & 15, lg = lane >> 4;
    const int c0 = cg * 192 + w * 48;

    f32x4 acc[3];
#pragma unroll
    for (int nt = 0; nt < 3; ++nt) acc[nt] = (f32x4){0.f, 0.f, 0.f, 0.f};

    const u16* ap = At + ((size_t)b * LP + l0 + lm) * DD + lg * 8;
    const u16* bp = Wb + (size_t)(c0 + lm) * DD + lg * 8;
#pragma unroll 4
    for (int ks = 0; ks < 16; ++ks) {
        bf16x8 aq = *reinterpret_cast<const bf16x8*>(ap + ks * 32);
#pragma unroll
        for (int nt = 0; nt < 3; ++nt) {
            bf16x8 bv = *reinterpret_cast<const bf16x8*>(bp + (size_t)nt * 16 * DD + ks * 32);
            acc[nt] = MFMA(aq, bv, acc[nt], 0, 0, 0);
        }
    }

    const int lq = l0 + lg * 4;   // quad start (pad rows produce zero acc)
#pragma unroll
    for (int nt = 0; nt < 3; ++nt) {
        int c = c0 + nt * 16 + lm;
        u16 pk[4];
#pragma unroll
        for (int r = 0; r < 4; ++r) pk[r] = f2bf(acc[nt][r]);
        uint2 pv; __builtin_memcpy(&pv, pk, 8);
        *reinterpret_cast<uint2*>(&tc[((size_t)b * CC + c) * LP2 + lq]) = pv;  // 8B aligned
#pragma unroll
        for (int r = 0; r < 4; ++r)
            tlc[((size_t)b * LP + lq + r) * CC + c] = pk[r];
    }
    if (tile == 4 && lg == 0) {   // zero tc K-pad l=80..95
        uint4 z = {0u, 0u, 0u, 0u};
#pragma unroll
        for (int nt = 0; nt < 3; ++nt) {
            int c = c0 + nt * 16 + lm;
            *reinterpret_cast<uint4*>(&tc[((size_t)b * CC + c) * LP2 + 80]) = z;
            *reinterpret_cast<uint4*>(&tc[((size_t)b * CC + c) * LP2 + 88]) = z;
        }
    }
}

// K2: fully fused, q read ONCE, 8 waves (512 thr): wave owns 96-col j-slice + 128-col K-window.
__global__ __launch_bounds__(512, 4) void k_fused(const u16* __restrict__ tc,
                                                  const u16* __restrict__ tlc,
                                                  const u16* __restrict__ Abf,
                                                  const float* __restrict__ q,
                                                  const float* __restrict__ gamma,
                                                  float* __restrict__ out) {
    __shared__ __align__(16) char un[8 * WREG2];   // 41472 B, per-wave union regions
    __shared__ __align__(16) char sh2[5120];       // qh_bf[16][96]u16, later us[16][80]f32
    __shared__ float pmax[128];
    __shared__ float psum[128];

    // ---- XCD swizzle: id&7 = xcd; each XCD owns 4 batches ----
    const int id = blockIdx.x;
    const int o = id >> 3;
    const int b = (id & 7) * 4 + o / 48;
    const int iBase = (o % 48) * 16;

    const int tid = threadIdx.x;
    const int wv = tid >> 6, lane = tid & 63;
    const int lm = lane & 15, lg = lane >> 4;
    const float g = gamma[0];

    // ---- 1. load q: 16 rows x 2 cols of this wave's K-window; stage to own qbuf ----
    const int c0 = wv * 128 + lane * 2;
    const size_t qRow = ((size_t)b * CC + iBase) * SS + c0;
    u32 qpk[16];
#pragma unroll
    for (int r = 0; r < 16; ++r) {
        f32x2 v = *reinterpret_cast<const f32x2*>(&q[qRow + (size_t)r * SS]);
        qpk[r] = (u32)f2bf(v[0]) | ((u32)f2bf(v[1]) << 16);
    }
    u16* qbuf = (u16*)(un + wv * WREG2);
#pragma unroll
    for (int r = 0; r < 16; ++r)
        *reinterpret_cast<u32*>(&qbuf[r * 136 + lane * 2]) = qpk[r];   // wave-private

    // ---- 2. qh[16x80] partial = q @ Ab^T over this wave's K=128 window ----
    f32x4 aqh[5];
#pragma unroll
    for (int nt = 0; nt < 5; ++nt) aqh[nt] = (f32x4){0.f, 0.f, 0.f, 0.f};
    const u16* abw = Abf + (size_t)wv * 10240 + lane * 8;
#pragma unroll
    for (int kk = 0; kk < 4; ++kk) {
        bf16x8 av = *reinterpret_cast<const bf16x8*>(&qbuf[lm * 136 + kk * 32 + lg * 8]);
#pragma unroll
        for (int nt = 0; nt < 5; ++nt) {
            bf16x8 bv = *reinterpret_cast<const bf16x8*>(abw + ((nt * 4 + kk) << 9));
            aqh[nt] = MFMA(av, bv, aqh[nt], 0, 0, 0);
        }
    }
    {   // write wave partial [16][80] f32 over own (now-dead) qbuf
        float* qp = (float*)(un + wv * WREG2);
#pragma unroll
        for (int nt = 0; nt < 5; ++nt) {
#pragma unroll
            for (int r = 0; r < 4; ++r)
                qp[(lg * 4 + r) * 80 + nt * 16 + lm] = aqh[nt][r];
        }
    }
    __syncthreads();   // B1: qh partials visible

    u16* qh_bf = (u16*)sh2;
#pragma unroll
    for (int k = 0; k < 3; ++k) {
        int e = tid + (k << 9);          // 1280 entries
        if (e < 1280) {
            int row = e / 80, l = e - row * 80;
            float v = 0.f;
#pragma unroll
            for (int i = 0; i < 8; ++i) v += ((float*)(un + i * WREG2))[row * 80 + l];
            qh_bf[row * 96 + l] = f2bf(v);   // l=77..79 exactly 0 (Ab rows are 0 there)
        }
    }
    if (tid < 256) qh_bf[(tid >> 4) * 96 + 80 + (tid & 15)] = 0;  // zero pad cols
    __syncthreads();   // B2: qh_bf ready

    // ---- 3. logits: A = qh_bf rows, B = tc rows of this wave's 96-col j-slice ----
    bf16x8 aq0 = *reinterpret_cast<const bf16x8*>(&qh_bf[lm * 96 + lg * 8]);
    bf16x8 aq1 = *reinterpret_cast<const bf16x8*>(&qh_bf[lm * 96 + 32 + lg * 8]);
    bf16x8 aq2 = *reinterpret_cast<const bf16x8*>(&qh_bf[lm * 96 + 64 + lg * 8]);

    f32x4 acc[6];
#pragma unroll
    for (int t = 0; t < 6; ++t) acc[t] = (f32x4){0.f, 0.f, 0.f, 0.f};

    const u16* tcb = tc + ((size_t)b * CC + wv * 96 + lm) * LP2 + lg * 8;
#pragma unroll
    for (int t = 0; t < 6; ++t) {
        const u16* p = tcb + (size_t)t * 16 * LP2;
        bf16x8 b0 = *reinterpret_cast<const bf16x8*>(p);
        bf16x8 b1 = *reinterpret_cast<const bf16x8*>(p + 32);
        bf16x8 b2 = *reinterpret_cast<const bf16x8*>(p + 64);
        acc[t] = MFMA(aq0, b0, acc[t], 0, 0, 0);
        acc[t] = MFMA(aq1, b1, acc[t], 0, 0, 0);
        acc[t] = MFMA(aq2, b2, acc[t], 0, 0, 0);
    }

    // ---- 4. softmax (C layout: col = lane&15, row = lg*4 + reg) ----
    float m[4];
#pragma unroll
    for (int r = 0; r < 4; ++r) {
        float mm = acc[0][r];
#pragma unroll
        for (int t = 1; t < 6; ++t) mm = fmaxf(mm, acc[t][r]);
#pragma unroll
        for (int off = 8; off >= 1; off >>= 1) mm = fmaxf(mm, __shfl_xor(mm, off));
        m[r] = mm;
    }
    if (lm == 0) {
#pragma unroll
        for (int r = 0; r < 4; ++r) pmax[wv * 16 + lg * 4 + r] = m[r];
    }
    __syncthreads();   // B3: pmax visible
    float gm[4];
#pragma unroll
    for (int r = 0; r < 4; ++r) {
        int row = lg * 4 + r;
        float a01 = fmaxf(pmax[row], pmax[16 + row]);
        float a23 = fmaxf(pmax[32 + row], pmax[48 + row]);
        float a45 = fmaxf(pmax[64 + row], pmax[80 + row]);
        float a67 = fmaxf(pmax[96 + row], pmax[112 + row]);
        gm[r] = fmaxf(fmaxf(a01, a23), fmaxf(a45, a67));
    }
    float s[4] = {0.f, 0.f, 0.f, 0.f};
#pragma unroll
    for (int t = 0; t < 6; ++t) {
#pragma unroll
        for (int r = 0; r < 4; ++r) {
            float e = __expf(acc[t][r] - gm[r]);
            acc[t][r] = e;
            s[r] += e;
        }
    }
#pragma unroll
    for (int r = 0; r < 4; ++r) {
#pragma unroll
        for (int off = 8; off >= 1; off >>= 1) s[r] += __shfl_xor(s[r], off);
    }
    if (lm == 0) {
#pragma unroll
        for (int r = 0; r < 4; ++r) psum[wv * 16 + lg * 4 + r] = s[r];
    }

    // ---- 5. P -> bf16 into own wave region, stride 104 (wave-private, no barrier) ----
    u16* P = (u16*)(un + wv * WREG2);
#pragma unroll
    for (int t = 0; t < 6; ++t) {
#pragma unroll
        for (int r = 0; r < 4; ++r)
            P[(lg * 4 + r) * 104 + t * 16 + lm] = f2bf(acc[t][r]);
    }

    // ---- 6. PV: u[16x80] += P[16x96] . tlc[96x80] (this wave's j-slice) ----
    f32x4 u[5];
#pragma unroll
    for (int nt = 0; nt < 5; ++nt) u[nt] = (f32x4){0.f, 0.f, 0.f, 0.f};
    const u16* tb = tlc + ((size_t)b * LP + lm) * CC + wv * 96 + lg * 8;
#pragma unroll
    for (int ks = 0; ks < 3; ++ks) {
        bf16x8 pa = *reinterpret_cast<const bf16x8*>(&P[lm * 104 + ks * 32 + lg * 8]);
#pragma unroll
        for (int nt = 0; nt < 5; ++nt) {
            bf16x8 bv = *reinterpret_cast<const bf16x8*>(tb + (size_t)nt * 16 * CC + ks * 32);
            u[nt] = MFMA(pa, bv, u[nt], 0, 0, 0);
        }
    }

    // ---- 7. cross-wave u reduce (own region overwrite; in-wave ordered) ----
    float* up = (float*)(un + wv * WREG2);
#pragma unroll
    for (int nt = 0; nt < 5; ++nt) {
#pragma unroll
        for (int r = 0; r < 4; ++r)
            up[(lg * 4 + r) * 81 + nt * 16 + lm] = u[nt][r];
    }
    __syncthreads();   // B4: u partials + psum visible
    float* us = (float*)sh2;   // qh_bf dead since logits frag loads
#pragma unroll
    for (int k = 0; k < 3; ++k) {
        int e = tid + (k << 9);
        if (e < 1280) {
            int row = e / 80, l = e - row * 80;
            float v = 0.f;
#pragma unroll
            for (int i = 0; i < 8; ++i) v += ((float*)(un + i * WREG2))[row * 81 + l];
            float denom = 0.f;
#pragma unroll
            for (int i = 0; i < 8; ++i) denom += psum[i * 16 + row];
            us[row * 80 + l] = v / denom;
        }
    }
    __syncthreads();   // B5: us ready

    // ---- 8. epilogue: out = q(bf16) + gamma * interp(us) for this wave's 2 cols x 16 rows ----
    float srcA = fminf(fmaxf(fmaf((float)c0 + 0.5f, RATIO, -0.5f), 0.f), 76.f);
    float srcB = fminf(fmaxf(fmaf((float)c0 + 1.5f, RATIO, -0.5f), 0.f), 76.f);
    int i0a = (int)srcA, i0b = (int)srcB;
    float wa = srcA - (float)i0a, wb = srcB - (float)i0b;
    int i1a = (i0a < 76) ? i0a + 1 : 76;
    int i1b = (i0b < 76) ? i0b + 1 : 76;
#pragma unroll
    for (int r = 0; r < 16; ++r) {
        const float* ur = &us[r * 80];
        float ua = fmaf(1.f - wa, ur[i0a], wa * ur[i1a]);
        float ub = fmaf(1.f - wb, ur[i0b], wb * ur[i1b]);
        u32 qq = qpk[r];
        f32x2 ov;
        ov[0] = bf2f(qq & 0xffffu) + g * ua;
        ov[1] = bf2f(qq >> 16) + g * ub;
        __builtin_nontemporal_store(ov, reinterpret_cast<f32x2*>(&out[qRow + (size_t)r * SS]));
    }
}

extern "C" void kernel_launch(void* const* d_in, const int* in_sizes, int n_in,
                              void* d_out, int out_size, void* d_ws, size_t ws_size,
                              hipStream_t stream) {
    const float* img   = (const float*)d_in[0];
    const float* text  = (const float*)d_in[1];
    const float* Wt    = (const float*)d_in[2];
    const float* gamma = (const float*)d_in[3];
    float* out = (float*)d_out;
    char* ws = (char*)d_ws;
    u16*   tc_bf  = (u16*)(ws);                   // 32*768*96*2 = 4,718,592
    u16*   tlc_bf = (u16*)(ws + 4718592);         // 32*80*768*2 = 3,932,160
    u16*   At_bf  = (u16*)(ws + 8650752);         // 32*80*512*2 = 2,621,440
    u16*   Wb_bf  = (u16*)(ws + 11272192);        // 768*512*2   =   786,432
    u16*   Abf_bf = (u16*)(ws + 12058624);        // 8*5*4*512*2 =   163,840  (end 12,222,464)

    k_cvt<<<dim3(CVT_TXT_BLOCKS + CVT_W_BLOCKS + AB_BLOCKS), 256, 0, stream>>>(
        text, Wt, At_bf, Wb_bf, Abf_bf);
    k_tgemm<<<dim3(TG_BLOCKS), 256, 0, stream>>>(At_bf, Wb_bf, tc_bf, tlc_bf);
    k_fused<<<dim3(48 * BB), 512, 0, stream>>>(tc_bf, tlc_bf, Abf_bf, img, gamma, out);
}

// Round 16
// 99.514 us; speedup vs baseline: 1.0235x; 1.0235x over previous
//
#include <hip/hip_runtime.h>

#define BB 32
#define CC 768
#define SS 1024
#define LLn 77
#define DD 512
#define LP 80      // padded L for tlc rows / At rows
#define LP2 96     // padded L (K dim) for bf16 MFMA operands, mult of 32
#define WREG2 5184 // bytes per wave union: qbuf[16][136]bf16 -> qhpart[16][80]f32 -> P[16][104]bf16 -> upart[16][81]f32

#define RATIO 0.0751953125f   // 77/1024 exact in fp32

#define CVT_TXT_BLOCKS (BB * LP * DD / 4 / 256)   // 1280
#define CVT_W_BLOCKS ((CC / 32) * (DD / 32))      // 384
#define AB_BLOCKS (8 * 5 * 4 * 64 * 8 / 4 / 256)  // 80 (fragment-layout Ab, 8 K-windows)
#define TG_BLOCKS (BB * 5 * 4)                    // 640

typedef short bf16x8 __attribute__((ext_vector_type(8)));
typedef float f32x4 __attribute__((ext_vector_type(4)));
typedef float f32x2 __attribute__((ext_vector_type(2)));
typedef unsigned short u16;
typedef unsigned int u32;

#define MFMA __builtin_amdgcn_mfma_f32_16x16x32_bf16

__device__ __forceinline__ float bf2f(unsigned int h16) {
    unsigned int u = h16 << 16;
    float f; __builtin_memcpy(&f, &u, 4); return f;
}
__device__ __forceinline__ u16 f2bf(float f) {
    unsigned int u; __builtin_memcpy(&u, &f, 4);
    u += 0x7fffu + ((u >> 16) & 1u);   // RNE
    return (u16)(u >> 16);
}

// K0: converts. text -> At bf16 (padded rows); W -> Wb bf16 transposed;
//     tent-weight matrix in MFMA-fragment layout for 8 waves x 5 ntiles x 4 ksteps.
__global__ __launch_bounds__(256) void k_cvt(const float* __restrict__ text,
                                             const float* __restrict__ Wt,
                                             u16* __restrict__ At,
                                             u16* __restrict__ Wb,
                                             u16* __restrict__ Abf) {
    __shared__ float tile[32 * 33];
    const int bx = blockIdx.x;
    const int tid = threadIdx.x;
    if (bx < CVT_TXT_BLOCKS) {
        int j = bx * 256 + tid;                    // float4-granular, exact cover
        int row80 = j >> 7, col4 = (j & 127) << 2;
        int b = row80 / LP, l = row80 - b * LP;
        u16 o[4] = {0, 0, 0, 0};
        if (l < LLn) {
            float4 v = *reinterpret_cast<const float4*>(&text[((size_t)b * LLn + l) * DD + col4]);
            o[0] = f2bf(v.x); o[1] = f2bf(v.y); o[2] = f2bf(v.z); o[3] = f2bf(v.w);
        }
        *reinterpret_cast<uint2*>(&At[(size_t)row80 * DD + col4]) = *reinterpret_cast<uint2*>(o);
    } else if (bx < CVT_TXT_BLOCKS + CVT_W_BLOCKS) {
        const int bw = bx - CVT_TXT_BLOCKS;
        const int c0 = (bw % (CC / 32)) * 32, d0 = (bw / (CC / 32)) * 32;
        const int tx = tid & 31, ty = tid >> 5;    // ty 0..7
#pragma unroll
        for (int k = 0; k < 4; ++k) {
            int d = ty + k * 8;
            tile[d * 33 + tx] = Wt[(size_t)(d0 + d) * CC + c0 + tx];
        }
        __syncthreads();
#pragma unroll
        for (int k = 0; k < 4; ++k) {
            int c = ty + k * 8;
            Wb[(size_t)(c0 + c) * DD + d0 + tx] = f2bf(tile[tx * 33 + c]);
        }
    } else {
        // ---- Abf: frag f = (wv*5+nt)*4+kk, elem = f*512 + lane*8 + e ----
        int g = (bx - CVT_TXT_BLOCKS - CVT_W_BLOCKS) * 1024 + tid * 4;  // 4 e-values/thread
        int e0   = g & 7;              // 0 or 4
        int lane = (g >> 3) & 63;
        int kk   = (g >> 9) & 3;
        int wn   = g >> 11;            // wv*5 + nt
        int nt   = wn % 5;
        int wv   = wn / 5;
        int l    = nt * 16 + (lane & 15);
        int sb   = wv * 128 + kk * 32 + ((lane >> 4) << 3) + e0;
        float fl = (float)l;
        u16 o[4];
#pragma unroll
        for (int k = 0; k < 4; ++k) {
            float src = fmaf((float)(sb + k) + 0.5f, RATIO, -0.5f);
            src = fminf(fmaxf(src, 0.f), 76.f);
            o[k] = f2bf(fmaxf(0.f, 1.f - fabsf(src - fl)) * 0.03125f);
        }
        *reinterpret_cast<uint2*>(&Abf[g]) = *reinterpret_cast<uint2*>(o);
    }
}

// K1: t = text @ W, batch-aligned tiles. 640 blocks: bx -> (colgroup, b, tile).
__global__ __launch_bounds__(256) void k_tgemm(const u16* __restrict__ At,
                                               const u16* __restrict__ Wb,
                                               u16* __restrict__ tc,
                                               u16* __restrict__ tlc) {
    const int bx = blockIdx.x;
    const int tid = threadIdx.x;
    const int cg = bx / 160, mt = bx % 160;
    const int b = mt / 5, tile = mt % 5;
    const int l0 = tile * 16;
    const int w = tid >> 6, lane = tid & 63;
    const int lm = lane & 15, lg = lane >> 4;
    const int c0 = cg * 192 + w * 48;

    f32x4 acc[3];
#pragma unroll
    for (int nt = 0; nt < 3; ++nt) acc[nt] = (f32x4){0.f, 0.f, 0.f, 0.f};

    const u16* ap = At + ((size_t)b * LP + l0 + lm) * DD + lg * 8;
    const u16* bp = Wb + (size_t)(c0 + lm) * DD + lg * 8;
#pragma unroll 4
    for (int ks = 0; ks < 16; ++ks) {
        bf16x8 aq = *reinterpret_cast<const bf16x8*>(ap + ks * 32);
#pragma unroll
        for (int nt = 0; nt < 3; ++nt) {
            bf16x8 bv = *reinterpret_cast<const bf16x8*>(bp + (size_t)nt * 16 * DD + ks * 32);
            acc[nt] = MFMA(aq, bv, acc[nt], 0, 0, 0);
        }
    }

    const int lq = l0 + lg * 4;   // quad start (pad rows produce zero acc)
#pragma unroll
    for (int nt = 0; nt < 3; ++nt) {
        int c = c0 + nt * 16 + lm;
        u16 pk[4];
#pragma unroll
        for (int r = 0; r < 4; ++r) pk[r] = f2bf(acc[nt][r]);
        uint2 pv; __builtin_memcpy(&pv, pk, 8);
        *reinterpret_cast<uint2*>(&tc[((size_t)b * CC + c) * LP2 + lq]) = pv;  // 8B aligned
#pragma unroll
        for (int r = 0; r < 4; ++r)
            tlc[((size_t)b * LP + lq + r) * CC + c] = pk[r];
    }
    if (tile == 4 && lg == 0) {   // zero tc K-pad l=80..95
        uint4 z = {0u, 0u, 0u, 0u};
#pragma unroll
        for (int nt = 0; nt < 3; ++nt) {
            int c = c0 + nt * 16 + lm;
            *reinterpret_cast<uint4*>(&tc[((size_t)b * CC + c) * LP2 + 80]) = z;
            *reinterpret_cast<uint4*>(&tc[((size_t)b * CC + c) * LP2 + 88]) = z;
        }
    }
}

// K2: fully fused, q read ONCE, 8 waves; FLASH-style per-wave local softmax:
// no barrier between logits and PV; single merge reduce at the end.
__global__ __launch_bounds__(512, 4) void k_fused(const u16* __restrict__ tc,
                                                  const u16* __restrict__ tlc,
                                                  const u16* __restrict__ Abf,
                                                  const float* __restrict__ q,
                                                  const float* __restrict__ gamma,
                                                  float* __restrict__ out) {
    __shared__ __align__(16) char un[8 * WREG2];   // 41472 B, per-wave union regions
    __shared__ __align__(16) char sh2[5120];       // qh_bf[16][96]u16, later us[16][80]f32
    __shared__ float pmax[128];
    __shared__ float psum[128];

    // ---- XCD swizzle: id&7 = xcd; each XCD owns 4 batches ----
    const int id = blockIdx.x;
    const int o = id >> 3;
    const int b = (id & 7) * 4 + o / 48;
    const int iBase = (o % 48) * 16;

    const int tid = threadIdx.x;
    const int wv = tid >> 6, lane = tid & 63;
    const int lm = lane & 15, lg = lane >> 4;
    const float g = gamma[0];

    // ---- 1. load q: 16 rows x 2 cols of this wave's K-window; stage to own qbuf ----
    const int c0 = wv * 128 + lane * 2;
    const size_t qRow = ((size_t)b * CC + iBase) * SS + c0;
    u32 qpk[16];
#pragma unroll
    for (int r = 0; r < 16; ++r) {
        f32x2 v = *reinterpret_cast<const f32x2*>(&q[qRow + (size_t)r * SS]);
        qpk[r] = (u32)f2bf(v[0]) | ((u32)f2bf(v[1]) << 16);
    }
    u16* qbuf = (u16*)(un + wv * WREG2);
#pragma unroll
    for (int r = 0; r < 16; ++r)
        *reinterpret_cast<u32*>(&qbuf[r * 136 + lane * 2]) = qpk[r];   // wave-private

    // ---- 2. qh[16x80] partial = q @ Ab^T over this wave's K=128 window ----
    f32x4 aqh[5];
#pragma unroll
    for (int nt = 0; nt < 5; ++nt) aqh[nt] = (f32x4){0.f, 0.f, 0.f, 0.f};
    const u16* abw = Abf + (size_t)wv * 10240 + lane * 8;
#pragma unroll
    for (int kk = 0; kk < 4; ++kk) {
        bf16x8 av = *reinterpret_cast<const bf16x8*>(&qbuf[lm * 136 + kk * 32 + lg * 8]);
#pragma unroll
        for (int nt = 0; nt < 5; ++nt) {
            bf16x8 bv = *reinterpret_cast<const bf16x8*>(abw + ((nt * 4 + kk) << 9));
            aqh[nt] = MFMA(av, bv, aqh[nt], 0, 0, 0);
        }
    }
    {   // write wave partial [16][80] f32 over own (now-dead) qbuf
        float* qp = (float*)(un + wv * WREG2);
#pragma unroll
        for (int nt = 0; nt < 5; ++nt) {
#pragma unroll
            for (int r = 0; r < 4; ++r)
                qp[(lg * 4 + r) * 80 + nt * 16 + lm] = aqh[nt][r];
        }
    }
    __syncthreads();   // B1: qh partials visible

    u16* qh_bf = (u16*)sh2;
#pragma unroll
    for (int k = 0; k < 3; ++k) {
        int e = tid + (k << 9);          // 1280 entries
        if (e < 1280) {
            int row = e / 80, l = e - row * 80;
            float v = 0.f;
#pragma unroll
            for (int i = 0; i < 8; ++i) v += ((float*)(un + i * WREG2))[row * 80 + l];
            qh_bf[row * 96 + l] = f2bf(v);   // l=77..79 exactly 0 (Ab rows are 0 there)
        }
    }
    if (tid < 256) qh_bf[(tid >> 4) * 96 + 80 + (tid & 15)] = 0;  // zero pad cols
    __syncthreads();   // B2: qh_bf ready

    // ---- 3. logits over this wave's 96-col j-slice (barrier-free through PV) ----
    bf16x8 aq0 = *reinterpret_cast<const bf16x8*>(&qh_bf[lm * 96 + lg * 8]);
    bf16x8 aq1 = *reinterpret_cast<const bf16x8*>(&qh_bf[lm * 96 + 32 + lg * 8]);
    bf16x8 aq2 = *reinterpret_cast<const bf16x8*>(&qh_bf[lm * 96 + 64 + lg * 8]);

    f32x4 acc[6];
#pragma unroll
    for (int t = 0; t < 6; ++t) acc[t] = (f32x4){0.f, 0.f, 0.f, 0.f};

    const u16* tcb = tc + ((size_t)b * CC + wv * 96 + lm) * LP2 + lg * 8;
#pragma unroll
    for (int t = 0; t < 6; ++t) {
        const u16* p = tcb + (size_t)t * 16 * LP2;
        bf16x8 b0 = *reinterpret_cast<const bf16x8*>(p);
        bf16x8 b1 = *reinterpret_cast<const bf16x8*>(p + 32);
        bf16x8 b2 = *reinterpret_cast<const bf16x8*>(p + 64);
        acc[t] = MFMA(aq0, b0, acc[t], 0, 0, 0);
        acc[t] = MFMA(aq1, b1, acc[t], 0, 0, 0);
        acc[t] = MFMA(aq2, b2, acc[t], 0, 0, 0);
    }

    // ---- 4. LOCAL softmax: wave-local max over its 96 cols (no cross-wave barrier) ----
    float m[4];
#pragma unroll
    for (int r = 0; r < 4; ++r) {
        float mm = acc[0][r];
#pragma unroll
        for (int t = 1; t < 6; ++t) mm = fmaxf(mm, acc[t][r]);
#pragma unroll
        for (int off = 8; off >= 1; off >>= 1) mm = fmaxf(mm, __shfl_xor(mm, off));
        m[r] = mm;
    }
    float s[4] = {0.f, 0.f, 0.f, 0.f};
#pragma unroll
    for (int t = 0; t < 6; ++t) {
#pragma unroll
        for (int r = 0; r < 4; ++r) {
            float e = __expf(acc[t][r] - m[r]);   // local max: e <= 1
            acc[t][r] = e;
            s[r] += e;
        }
    }
#pragma unroll
    for (int r = 0; r < 4; ++r) {
#pragma unroll
        for (int off = 8; off >= 1; off >>= 1) s[r] += __shfl_xor(s[r], off);
    }
    if (lm == 0) {
#pragma unroll
        for (int r = 0; r < 4; ++r) {
            pmax[wv * 16 + lg * 4 + r] = m[r];
            psum[wv * 16 + lg * 4 + r] = s[r];
        }
    }

    // ---- 5. P -> bf16 into own wave region (wave-private, no barrier) ----
    u16* P = (u16*)(un + wv * WREG2);
#pragma unroll
    for (int t = 0; t < 6; ++t) {
#pragma unroll
        for (int r = 0; r < 4; ++r)
            P[(lg * 4 + r) * 104 + t * 16 + lm] = f2bf(acc[t][r]);
    }

    // ---- 6. PV with LOCAL-max P: u_w[16x80] = P_w . tlc_w (barrier-free) ----
    f32x4 u[5];
#pragma unroll
    for (int nt = 0; nt < 5; ++nt) u[nt] = (f32x4){0.f, 0.f, 0.f, 0.f};
    const u16* tb = tlc + ((size_t)b * LP + lm) * CC + wv * 96 + lg * 8;
#pragma unroll
    for (int ks = 0; ks < 3; ++ks) {
        bf16x8 pa = *reinterpret_cast<const bf16x8*>(&P[lm * 104 + ks * 32 + lg * 8]);
#pragma unroll
        for (int nt = 0; nt < 5; ++nt) {
            bf16x8 bv = *reinterpret_cast<const bf16x8*>(tb + (size_t)nt * 16 * CC + ks * 32);
            u[nt] = MFMA(pa, bv, u[nt], 0, 0, 0);
        }
    }

    // ---- 7. write u_w partial; ONE merge barrier; flash-rescale combine ----
    float* up = (float*)(un + wv * WREG2);
#pragma unroll
    for (int nt = 0; nt < 5; ++nt) {
#pragma unroll
        for (int r = 0; r < 4; ++r)
            up[(lg * 4 + r) * 81 + nt * 16 + lm] = u[nt][r];
    }
    __syncthreads();   // B3: u partials + pmax/psum visible
    float* us = (float*)sh2;   // qh_bf dead since logits frag loads
#pragma unroll
    for (int k = 0; k < 3; ++k) {
        int e = tid + (k << 9);
        if (e < 1280) {
            int row = e / 80, l = e - row * 80;
            // global max over 8 wave-local maxes
            float mg = pmax[row];
#pragma unroll
            for (int i = 1; i < 8; ++i) mg = fmaxf(mg, pmax[i * 16 + row]);
            float num = 0.f, den = 0.f;
#pragma unroll
            for (int i = 0; i < 8; ++i) {
                float fac = __expf(pmax[i * 16 + row] - mg);
                num = fmaf(((float*)(un + i * WREG2))[row * 81 + l], fac, num);
                den = fmaf(psum[i * 16 + row], fac, den);
            }
            us[row * 80 + l] = num / den;
        }
    }
    __syncthreads();   // B4: us ready

    // ---- 8. epilogue: out = q(bf16) + gamma * interp(us) for this wave's 2 cols x 16 rows ----
    float srcA = fminf(fmaxf(fmaf((float)c0 + 0.5f, RATIO, -0.5f), 0.f), 76.f);
    float srcB = fminf(fmaxf(fmaf((float)c0 + 1.5f, RATIO, -0.5f), 0.f), 76.f);
    int i0a = (int)srcA, i0b = (int)srcB;
    float wa = srcA - (float)i0a, wb = srcB - (float)i0b;
    int i1a = (i0a < 76) ? i0a + 1 : 76;
    int i1b = (i0b < 76) ? i0b + 1 : 76;
#pragma unroll
    for (int r = 0; r < 16; ++r) {
        const float* ur = &us[r * 80];
        float ua = fmaf(1.f - wa, ur[i0a], wa * ur[i1a]);
        float ub = fmaf(1.f - wb, ur[i0b], wb * ur[i1b]);
        u32 qq = qpk[r];
        f32x2 ov;
        ov[0] = bf2f(qq & 0xffffu) + g * ua;
        ov[1] = bf2f(qq >> 16) + g * ub;
        __builtin_nontemporal_store(ov, reinterpret_cast<f32x2*>(&out[qRow + (size_t)r * SS]));
    }
}

extern "C" void kernel_launch(void* const* d_in, const int* in_sizes, int n_in,
                              void* d_out, int out_size, void* d_ws, size_t ws_size,
                              hipStream_t stream) {
    const float* img   = (const float*)d_in[0];
    const float* text  = (const float*)d_in[1];
    const float* Wt    = (const float*)d_in[2];
    const float* gamma = (const float*)d_in[3];
    float* out = (float*)d_out;
    char* ws = (char*)d_ws;
    u16*   tc_bf  = (u16*)(ws);                   // 32*768*96*2 = 4,718,592
    u16*   tlc_bf = (u16*)(ws + 4718592);         // 32*80*768*2 = 3,932,160
    u16*   At_bf  = (u16*)(ws + 8650752);         // 32*80*512*2 = 2,621,440
    u16*   Wb_bf  = (u16*)(ws + 11272192);        // 768*512*2   =   786,432
    u16*   Abf_bf = (u16*)(ws + 12058624);        // 8*5*4*512*2 =   163,840  (end 12,222,464)

    k_cvt<<<dim3(CVT_TXT_BLOCKS + CVT_W_BLOCKS + AB_BLOCKS), 256, 0, stream>>>(
        text, Wt, At_bf, Wb_bf, Abf_bf);
    k_tgemm<<<dim3(TG_BLOCKS), 256, 0, stream>>>(At_bf, Wb_bf, tc_bf, tlc_bf);
    k_fused<<<dim3(48 * BB), 512, 0, stream>>>(tc_bf, tlc_bf, Abf_bf, img, gamma, out);
}